// Round 3
// baseline (1996.493 us; speedup 1.0000x reference)
//
#include <hip/hip_runtime.h>
#include <hip/hip_bf16.h>
#include <hip/hip_fp16.h>

typedef unsigned short u16;
typedef unsigned int u32;
typedef __attribute__((ext_vector_type(8))) _Float16 f16x8;
typedef __attribute__((ext_vector_type(4))) float f32x4;

#define ROWS 32          // 16 s/g pairs per block
#define SSTR 520         // slab stride in u16 (+8 pad: conflict-free b128)
#define NEG_INF (-3.0e38f)

__device__ __forceinline__ float bf2f(u16 b) {
  union { u32 u; float f; } c; c.u = ((u32)b) << 16; return c.f;
}
__device__ __forceinline__ u16 f2bf(float f) {
  union { float f; u32 u; } c; c.f = f;
  u32 r = c.u + 0x7FFFu + ((c.u >> 16) & 1u);
  return (u16)(r >> 16);
}
__device__ __forceinline__ float gelu_tanh(float x) {
  // jax.nn.gelu approximate=True
  float u = 0.7978845608028654f * (x + 0.044715f * x * x * x);
  float e = __expf(2.f * u);
  float t = 1.f - 2.f / (e + 1.f);
  return 0.5f * x * (1.f + t);
}
// load a scalar param that may be fp32 or bf16
__device__ __forceinline__ float ldp(const void* p, int i, int f32) {
  return f32 ? ((const float*)p)[i] : bf2f(((const u16*)p)[i]);
}
// load 8 consecutive elements (fp32 or bf16) as f16x8
__device__ __forceinline__ f16x8 load8(const void* base, long off, int f32) {
  f16x8 r;
  if (f32) {
    const float* p = (const float*)base + off;
#pragma unroll
    for (int i = 0; i < 8; ++i) r[i] = (_Float16)p[i];
  } else {
    const u16* p = (const u16*)base + off;
#pragma unroll
    for (int i = 0; i < 8; ++i) r[i] = (_Float16)bf2f(p[i]);
  }
  return r;
}

// one wave: decide whether inputs are fp32 (flag=1) or bf16 (flag=0).
// Even-indexed u16s of fp32 data are random mantissa halves -> huge bf16 values.
__global__ void detect_dtype(const u16* __restrict__ obs, int* flag) {
  int l = threadIdx.x;
  float v = fabsf(bf2f(obs[2 * l]));
  if (v != v) v = 1e30f;  // NaN pattern also implies fp32
#pragma unroll
  for (int m = 1; m <= 32; m <<= 1) v = fmaxf(v, __shfl_xor(v, m, 64));
  if (l == 0) *flag = (v > 1000.0f) ? 1 : 0;
}

// transpose W [K x 512] -> wT [512 x K] (row-major, K contiguous), cast to fp16
__global__ void pack_w(const void* __restrict__ src, u16* __restrict__ dst,
                       const int* __restrict__ flag, int total, int kshift, int kmask) {
  int id = blockIdx.x * 256 + threadIdx.x;
  if (id >= total) return;
  int n = id >> kshift, k = id & kmask;
  float v = ldp(src, k * 512 + n, *flag);
  dst[id] = __half_as_ushort(__float2half(v));
}

__global__ __launch_bounds__(512) void gciqe_main(
    const void* __restrict__ obs, const void* __restrict__ goals,
    const u16* __restrict__ wT0, const u16* __restrict__ wT1,
    const u16* __restrict__ wT2, const u16* __restrict__ wT3,
    const void* __restrict__ b0, const void* __restrict__ b1,
    const void* __restrict__ b2, const void* __restrict__ b3,
    const void* __restrict__ ls0, const void* __restrict__ lb0,
    const void* __restrict__ ls1, const void* __restrict__ lb1,
    const void* __restrict__ ls2, const void* __restrict__ lb2,
    const void* __restrict__ alphap, void* __restrict__ out,
    const int* __restrict__ flagp)
{
  __shared__ u16 slab[ROWS * SSTR];   // activations / phi, fp16 bits
  __shared__ float red[ROWS * 16];    // LN partials: [row][wave]{sum,sumsq}

  const int f32 = *flagp;
  const int tid = threadIdx.x;
  const int lane = tid & 63, w = tid >> 6;      // 8 waves = 8 groups of 64 ch
  const int r = lane & 15, q = lane >> 4;
  const int i0 = blockIdx.x * 16;               // 16 pairs per block

  f32x4 acc[4][2];                              // [ci: 16-ch group][nt: row half]

  // ---------------- layer 0: [32 x 64] @ W0 -> acc ----------------
#pragma unroll
  for (int ci = 0; ci < 4; ++ci) {
    acc[ci][0] = (f32x4){0.f, 0.f, 0.f, 0.f};
    acc[ci][1] = (f32x4){0.f, 0.f, 0.f, 0.f};
  }
  {
    f16x8 bf0[2][2];
#pragma unroll
    for (int nt = 0; nt < 2; ++nt) {
      int row = nt * 16 + r;                    // even = obs, odd = goals
      const void* base = (row & 1) ? goals : obs;
      long ro = (long)(i0 + (row >> 1)) * 64;
#pragma unroll
      for (int u = 0; u < 2; ++u)
        bf0[nt][u] = load8(base, ro + u * 32 + q * 8, f32);
    }
#pragma unroll
    for (int ci = 0; ci < 4; ++ci) {
      int ch = w * 64 + ci * 16 + r;
#pragma unroll
      for (int u = 0; u < 2; ++u) {
        f16x8 af = *(const f16x8*)(wT0 + ch * 64 + u * 32 + q * 8);
        acc[ci][0] = __builtin_amdgcn_mfma_f32_16x16x32_f16(af, bf0[0][u], acc[ci][0], 0, 0, 0);
        acc[ci][1] = __builtin_amdgcn_mfma_f32_16x16x32_f16(af, bf0[1][u], acc[ci][1], 0, 0, 0);
      }
    }
  }

  // ---------------- layers 0..2 epilogue + layers 1..3 GEMM ----------------
  for (int l = 0; l <= 3; ++l) {
    if (l > 0) {
      const u16* wp = (l == 1) ? wT1 : (l == 2) ? wT2 : wT3;
#pragma unroll
      for (int ci = 0; ci < 4; ++ci) {
        acc[ci][0] = (f32x4){0.f, 0.f, 0.f, 0.f};
        acc[ci][1] = (f32x4){0.f, 0.f, 0.f, 0.f};
      }
#pragma unroll
      for (int kq = 0; kq < 4; ++kq) {          // K in chunks of 128
        f16x8 bfr[2][4];
#pragma unroll
        for (int nt = 0; nt < 2; ++nt)
#pragma unroll
          for (int u = 0; u < 4; ++u)
            bfr[nt][u] = *(const f16x8*)(slab + (nt * 16 + r) * SSTR + kq * 128 + u * 32 + q * 8);
#pragma unroll
        for (int ci = 0; ci < 4; ++ci) {
          const u16* abase = wp + (w * 64 + ci * 16 + r) * 512 + kq * 128;
#pragma unroll
          for (int u = 0; u < 4; ++u) {
            f16x8 af = *(const f16x8*)(abase + u * 32 + q * 8);
            acc[ci][0] = __builtin_amdgcn_mfma_f32_16x16x32_f16(af, bfr[0][u], acc[ci][0], 0, 0, 0);
            acc[ci][1] = __builtin_amdgcn_mfma_f32_16x16x32_f16(af, bfr[1][u], acc[ci][1], 0, 0, 0);
          }
        }
      }
    }

    if (l < 3) {
      // ---- bias + gelu + LayerNorm -> slab (fp16) ----
      const void* pb  = (l == 0) ? b0 : (l == 1) ? b1 : b2;
      const void* psl = (l == 0) ? ls0 : (l == 1) ? ls1 : ls2;
      const void* plb = (l == 0) ? lb0 : (l == 1) ? lb1 : lb2;
      float bz[4][4];
#pragma unroll
      for (int ci = 0; ci < 4; ++ci) {
        int cb = w * 64 + ci * 16 + q * 4;
#pragma unroll
        for (int j = 0; j < 4; ++j) bz[ci][j] = ldp(pb, cb + j, f32);
      }
      float s[2] = {0.f, 0.f}, t[2] = {0.f, 0.f};
#pragma unroll
      for (int ci = 0; ci < 4; ++ci)
#pragma unroll
        for (int nt = 0; nt < 2; ++nt) {
          f32x4 v = acc[ci][nt];
          v.x = gelu_tanh(v.x + bz[ci][0]); v.y = gelu_tanh(v.y + bz[ci][1]);
          v.z = gelu_tanh(v.z + bz[ci][2]); v.w = gelu_tanh(v.w + bz[ci][3]);
          acc[ci][nt] = v;
          s[nt] += v.x + v.y + v.z + v.w;
          t[nt] += v.x * v.x + v.y * v.y + v.z * v.z + v.w * v.w;
        }
#pragma unroll
      for (int nt = 0; nt < 2; ++nt) {
        s[nt] += __shfl_xor(s[nt], 16, 64); t[nt] += __shfl_xor(t[nt], 16, 64);
        s[nt] += __shfl_xor(s[nt], 32, 64); t[nt] += __shfl_xor(t[nt], 32, 64);
      }
      if (q == 0) {
        *(float2*)(red + (0 * 16 + r) * 16 + w * 2) = make_float2(s[0], t[0]);
        *(float2*)(red + (1 * 16 + r) * 16 + w * 2) = make_float2(s[1], t[1]);
      }
      __syncthreads();   // also orders slab reads (GEMM) before slab writes below
      float mean[2], rstd[2];
#pragma unroll
      for (int nt = 0; nt < 2; ++nt) {
        int row = nt * 16 + r;
        float ts = 0.f, tq = 0.f;
#pragma unroll
        for (int p = 0; p < 4; ++p) {
          f32x4 a = *(const f32x4*)(red + row * 16 + p * 4);
          ts += a.x + a.z; tq += a.y + a.w;
        }
        mean[nt] = ts * (1.f / 512.f);
        rstd[nt] = rsqrtf(tq * (1.f / 512.f) - mean[nt] * mean[nt] + 1e-6f);
      }
      float gs[4][4], gb[4][4];
#pragma unroll
      for (int ci = 0; ci < 4; ++ci) {
        int cb = w * 64 + ci * 16 + q * 4;
#pragma unroll
        for (int j = 0; j < 4; ++j) {
          gs[ci][j] = ldp(psl, cb + j, f32);
          gb[ci][j] = ldp(plb, cb + j, f32);
        }
      }
#pragma unroll
      for (int ci = 0; ci < 4; ++ci) {
        int cb = w * 64 + ci * 16 + q * 4;
#pragma unroll
        for (int nt = 0; nt < 2; ++nt) {
          int row = nt * 16 + r;
          f32x4 v = acc[ci][nt];
          ushort4 o;
          o.x = __half_as_ushort(__float2half((v.x - mean[nt]) * rstd[nt] * gs[ci][0] + gb[ci][0]));
          o.y = __half_as_ushort(__float2half((v.y - mean[nt]) * rstd[nt] * gs[ci][1] + gb[ci][1]));
          o.z = __half_as_ushort(__float2half((v.z - mean[nt]) * rstd[nt] * gs[ci][2] + gb[ci][2]));
          o.w = __half_as_ushort(__float2half((v.w - mean[nt]) * rstd[nt] * gs[ci][3] + gb[ci][3]));
          *(ushort4*)(slab + row * SSTR + cb) = o;
        }
      }
      __syncthreads();
    } else {
      // ---- layer 3: bias only; store phi as fp16 ----
#pragma unroll
      for (int ci = 0; ci < 4; ++ci) {
        int cb = w * 64 + ci * 16 + q * 4;
        float bx = ldp(b3, cb + 0, f32), by = ldp(b3, cb + 1, f32);
        float bz2 = ldp(b3, cb + 2, f32), bw = ldp(b3, cb + 3, f32);
#pragma unroll
        for (int nt = 0; nt < 2; ++nt) {
          int row = nt * 16 + r;
          f32x4 v = acc[ci][nt];
          ushort4 o;
          o.x = __half_as_ushort(__float2half(v.x + bx));
          o.y = __half_as_ushort(__float2half(v.y + by));
          o.z = __half_as_ushort(__float2half(v.z + bz2));
          o.w = __half_as_ushort(__float2half(v.w + bw));
          *(ushort4*)(slab + row * SSTR + cb) = o;
        }
      }
      __syncthreads();
    }
  }

  // ---------------- IQE head ----------------
  {
    const float al = ldp(alphap, 0, f32);
    const float a = 1.f / (1.f + __expf(-al));
    const int h = lane >> 5, il = lane & 31;    // two components per wave
    for (int v = 0; v < 2; ++v) {
      int pL = 2 * w + v;                       // block-local pair 0..15
      float cs = 0.f, cm = 0.f;
      for (int it = 0; it < 8; ++it) {
        int c = 2 * it + h;                     // component 0..15
        float x = __half2float(__ushort_as_half(slab[(2 * pL) * SSTR + c * 32 + il]));
        float y = __half2float(__ushort_as_half(slab[(2 * pL + 1) * SSTR + c * 32 + il]));
        if (!(x < y)) y = NEG_INF;              // invalid interval -> empty
        // bitonic sort (x asc) across each 32-lane half, y rides along
#pragma unroll
        for (int k = 2; k <= 32; k <<= 1) {
#pragma unroll
          for (int j = k >> 1; j >= 1; j >>= 1) {
            float xo = __shfl_xor(x, j, 64);
            float yo = __shfl_xor(y, j, 64);
            bool keep_min = (((il & k) == 0) == ((il & j) == 0));
            bool take = keep_min ? (xo < x) : (xo > x);
            if (take) { x = xo; y = yo; }
          }
        }
        // exclusive prefix-max of y in start-sorted order
        float p = __shfl_up(y, 1, 32);
        if (il == 0) p = NEG_INF;
#pragma unroll
        for (int d = 1; d <= 16; d <<= 1) {
          float t2 = __shfl_up(p, d, 32);
          if (il >= d) p = fmaxf(p, t2);
        }
        float contrib = fmaxf(0.f, y - fmaxf(x, p));
#pragma unroll
        for (int msk = 1; msk <= 16; msk <<= 1)
          contrib += __shfl_xor(contrib, msk, 64);
        cs += contrib;
        cm = fmaxf(cm, contrib);
      }
      cs += __shfl_xor(cs, 32, 64);
      cm = fmaxf(cm, __shfl_xor(cm, 32, 64));
      if (lane == 0) {
        float res = a * (cs * (1.f / 16.f)) + (1.f - a) * cm;
        if (f32) ((float*)out)[i0 + pL] = res;
        else ((u16*)out)[i0 + pL] = f2bf(res);
      }
    }
  }
}

extern "C" void kernel_launch(void* const* d_in, const int* in_sizes, int n_in,
                              void* d_out, int out_size, void* d_ws, size_t ws_size,
                              hipStream_t stream) {
  (void)in_sizes; (void)n_in; (void)out_size; (void)ws_size;
  const void* obs   = d_in[0];
  const void* goals = d_in[1];
  const void* W0 = d_in[2];
  const void* b0 = d_in[3];
  const void* ls0 = d_in[4];
  const void* lb0 = d_in[5];
  const void* W1 = d_in[6];
  const void* b1 = d_in[7];
  const void* ls1 = d_in[8];
  const void* lb1 = d_in[9];
  const void* W2 = d_in[10];
  const void* b2 = d_in[11];
  const void* ls2 = d_in[12];
  const void* lb2 = d_in[13];
  const void* W3 = d_in[14];
  const void* b3 = d_in[15];
  const void* alpha = d_in[16];

  int* flag = (int*)d_ws;
  u16* wT0 = (u16*)((char*)d_ws + 64);
  u16* wT1 = wT0 + 512 * 64;
  u16* wT2 = wT1 + 512 * 512;
  u16* wT3 = wT2 + 512 * 512;

  detect_dtype<<<1, 64, 0, stream>>>((const u16*)obs, flag);
  pack_w<<<128, 256, 0, stream>>>(W0, wT0, flag, 512 * 64, 6, 63);
  pack_w<<<1024, 256, 0, stream>>>(W1, wT1, flag, 512 * 512, 9, 511);
  pack_w<<<1024, 256, 0, stream>>>(W2, wT2, flag, 512 * 512, 9, 511);
  pack_w<<<1024, 256, 0, stream>>>(W3, wT3, flag, 512 * 512, 9, 511);
  gciqe_main<<<8192, 512, 0, stream>>>(obs, goals, wT0, wT1, wT2, wT3,
      b0, b1, b2, b3, ls0, lb0, ls1, lb1, ls2, lb2, alpha, d_out, flag);
}

// Round 4
// 1996.167 us; speedup vs baseline: 1.0002x; 1.0002x over previous
//
#include <hip/hip_runtime.h>
#include <hip/hip_bf16.h>
#include <hip/hip_fp16.h>

typedef unsigned short u16;
typedef unsigned int u32;
typedef __attribute__((ext_vector_type(8))) _Float16 f16x8;
typedef __attribute__((ext_vector_type(4))) float f32x4;

#define ROWS 32          // 16 s/g pairs per block
#define SSTR 520         // slab stride in u16 (1040B: r vs r+8 2-way only)
#define RSTR 20          // red stride in floats (16B-aligned, 2-way only)
#define NEG_INF (-3.0e38f)

__device__ __forceinline__ float bf2f(u16 b) {
  union { u32 u; float f; } c; c.u = ((u32)b) << 16; return c.f;
}
__device__ __forceinline__ u16 f2bf(float f) {
  union { float f; u32 u; } c; c.f = f;
  u32 r = c.u + 0x7FFFu + ((c.u >> 16) & 1u);
  return (u16)(r >> 16);
}
__device__ __forceinline__ float gelu_tanh(float x) {
  // jax.nn.gelu approximate=True
  float u = 0.7978845608028654f * (x + 0.044715f * x * x * x);
  float e = __expf(2.f * u);
  float t = 1.f - 2.f / (e + 1.f);
  return 0.5f * x * (1.f + t);
}
// load a scalar param that may be fp32 or bf16
__device__ __forceinline__ float ldp(const void* p, int i, int f32) {
  return f32 ? ((const float*)p)[i] : bf2f(((const u16*)p)[i]);
}
// load 8 consecutive elements (fp32 or bf16) as f16x8 (vectorized)
__device__ __forceinline__ f16x8 load8(const void* base, long off, int f32) {
  f16x8 r;
  if (f32) {
    const float4* p = (const float4*)((const float*)base + off);
    float4 a = p[0], b = p[1];
    r[0] = (_Float16)a.x; r[1] = (_Float16)a.y; r[2] = (_Float16)a.z; r[3] = (_Float16)a.w;
    r[4] = (_Float16)b.x; r[5] = (_Float16)b.y; r[6] = (_Float16)b.z; r[7] = (_Float16)b.w;
  } else {
    const u16* p = (const u16*)base + off;
#pragma unroll
    for (int i = 0; i < 8; ++i) r[i] = (_Float16)bf2f(p[i]);
  }
  return r;
}

// one wave: decide whether inputs are fp32 (flag=1) or bf16 (flag=0).
__global__ void detect_dtype(const u16* __restrict__ obs, int* flag) {
  int l = threadIdx.x;
  float v = fabsf(bf2f(obs[2 * l]));
  if (v != v) v = 1e30f;  // NaN pattern also implies fp32
#pragma unroll
  for (int m = 1; m <= 32; m <<= 1) v = fmaxf(v, __shfl_xor(v, m, 64));
  if (l == 0) *flag = (v > 1000.0f) ? 1 : 0;
}

// transpose W [K x 512] -> wT [512 x K] (row-major, K contiguous), cast to fp16
__global__ void pack_w(const void* __restrict__ src, u16* __restrict__ dst,
                       const int* __restrict__ flag, int total, int kshift, int kmask) {
  int id = blockIdx.x * 256 + threadIdx.x;
  if (id >= total) return;
  int n = id >> kshift, k = id & kmask;
  float v = ldp(src, k * 512 + n, *flag);
  dst[id] = __half_as_ushort(__float2half(v));
}

__global__ __launch_bounds__(512, 4) void gciqe_main(
    const void* __restrict__ obs, const void* __restrict__ goals,
    const u16* __restrict__ wT0, const u16* __restrict__ wT1,
    const u16* __restrict__ wT2, const u16* __restrict__ wT3,
    const void* __restrict__ b0, const void* __restrict__ b1,
    const void* __restrict__ b2, const void* __restrict__ b3,
    const void* __restrict__ ls0, const void* __restrict__ lb0,
    const void* __restrict__ ls1, const void* __restrict__ lb1,
    const void* __restrict__ ls2, const void* __restrict__ lb2,
    const void* __restrict__ alphap, void* __restrict__ out,
    const int* __restrict__ flagp)
{
  __shared__ __align__(16) u16 slab[ROWS * SSTR];   // activations / phi, fp16 bits
  __shared__ __align__(16) float red[ROWS * RSTR];  // LN partials [row][wave]{s,t}

  const int f32 = *flagp;
  const int tid = threadIdx.x;
  const int lane = tid & 63, w = tid >> 6;      // 8 waves = 8 groups of 64 ch
  const int r = lane & 15, q = lane >> 4;
  const int i0 = blockIdx.x * 16;               // 16 pairs per block

  f32x4 acc[4][2];                              // [ci: 16-ch group][nt: row half]

  // ---------------- layer 0: [32 x 64] @ W0 -> acc ----------------
#pragma unroll
  for (int ci = 0; ci < 4; ++ci) {
    acc[ci][0] = (f32x4){0.f, 0.f, 0.f, 0.f};
    acc[ci][1] = (f32x4){0.f, 0.f, 0.f, 0.f};
  }
  {
    f16x8 bf0[2][2];
#pragma unroll
    for (int nt = 0; nt < 2; ++nt) {
      int row = nt * 16 + r;                    // even = obs, odd = goals
      const void* base = (row & 1) ? goals : obs;
      long ro = (long)(i0 + (row >> 1)) * 64;
#pragma unroll
      for (int u = 0; u < 2; ++u)
        bf0[nt][u] = load8(base, ro + u * 32 + q * 8, f32);
    }
#pragma unroll
    for (int ci = 0; ci < 4; ++ci) {
      int ch = w * 64 + ci * 16 + r;
#pragma unroll
      for (int u = 0; u < 2; ++u) {
        f16x8 af = *(const f16x8*)(wT0 + ch * 64 + u * 32 + q * 8);
        acc[ci][0] = __builtin_amdgcn_mfma_f32_16x16x32_f16(af, bf0[0][u], acc[ci][0], 0, 0, 0);
        acc[ci][1] = __builtin_amdgcn_mfma_f32_16x16x32_f16(af, bf0[1][u], acc[ci][1], 0, 0, 0);
      }
    }
  }

  // ---------------- layers 0..2 epilogue + layers 1..3 GEMM ----------------
  for (int l = 0; l <= 3; ++l) {
    if (l > 0) {
      const u16* wp = (l == 1) ? wT1 : (l == 2) ? wT2 : wT3;
      const u16* wrow = wp + (w * 64 + r) * 512;   // this lane's weight-row base
#pragma unroll
      for (int ci = 0; ci < 4; ++ci) {
        acc[ci][0] = (f32x4){0.f, 0.f, 0.f, 0.f};
        acc[ci][1] = (f32x4){0.f, 0.f, 0.f, 0.f};
      }
      // A-fragment register double-buffer: prefetch next (ci,kq) tile
      f16x8 A[2][4];
#pragma unroll
      for (int u = 0; u < 4; ++u)
        A[0][u] = *(const f16x8*)(wrow + 0 * 8192 + 0 * 128 + u * 32 + q * 8);
#pragma unroll
      for (int kq = 0; kq < 4; ++kq) {          // K in chunks of 128
        f16x8 bfr[2][4];
#pragma unroll
        for (int nt = 0; nt < 2; ++nt)
#pragma unroll
          for (int u = 0; u < 4; ++u)
            bfr[nt][u] = *(const f16x8*)(slab + (nt * 16 + r) * SSTR + kq * 128 + u * 32 + q * 8);
#pragma unroll
        for (int ci = 0; ci < 4; ++ci) {
          const int step = kq * 4 + ci;
          const int cur = step & 1;
          // prefetch the NEXT tile's A-fragments before this tile's MFMAs
          if (step < 15) {
            const int nstep = step + 1;
            const int nci = nstep & 3, nkq = nstep >> 2;
#pragma unroll
            for (int u = 0; u < 4; ++u)
              A[cur ^ 1][u] = *(const f16x8*)(wrow + nci * 8192 + nkq * 128 + u * 32 + q * 8);
          }
#pragma unroll
          for (int u = 0; u < 4; ++u) {
            acc[ci][0] = __builtin_amdgcn_mfma_f32_16x16x32_f16(A[cur][u], bfr[0][u], acc[ci][0], 0, 0, 0);
            acc[ci][1] = __builtin_amdgcn_mfma_f32_16x16x32_f16(A[cur][u], bfr[1][u], acc[ci][1], 0, 0, 0);
          }
        }
      }
    }

    if (l < 3) {
      // ---- bias + gelu + LayerNorm -> slab (fp16) ----
      const void* pb  = (l == 0) ? b0 : (l == 1) ? b1 : b2;
      const void* psl = (l == 0) ? ls0 : (l == 1) ? ls1 : ls2;
      const void* plb = (l == 0) ? lb0 : (l == 1) ? lb1 : lb2;
      float bz[4][4];
#pragma unroll
      for (int ci = 0; ci < 4; ++ci) {
        int cb = w * 64 + ci * 16 + q * 4;
#pragma unroll
        for (int j = 0; j < 4; ++j) bz[ci][j] = ldp(pb, cb + j, f32);
      }
      float s[2] = {0.f, 0.f}, t[2] = {0.f, 0.f};
#pragma unroll
      for (int ci = 0; ci < 4; ++ci)
#pragma unroll
        for (int nt = 0; nt < 2; ++nt) {
          f32x4 v = acc[ci][nt];
          v.x = gelu_tanh(v.x + bz[ci][0]); v.y = gelu_tanh(v.y + bz[ci][1]);
          v.z = gelu_tanh(v.z + bz[ci][2]); v.w = gelu_tanh(v.w + bz[ci][3]);
          acc[ci][nt] = v;
          s[nt] += v.x + v.y + v.z + v.w;
          t[nt] += v.x * v.x + v.y * v.y + v.z * v.z + v.w * v.w;
        }
#pragma unroll
      for (int nt = 0; nt < 2; ++nt) {
        s[nt] += __shfl_xor(s[nt], 16, 64); t[nt] += __shfl_xor(t[nt], 16, 64);
        s[nt] += __shfl_xor(s[nt], 32, 64); t[nt] += __shfl_xor(t[nt], 32, 64);
      }
      if (q == 0) {
        *(float2*)(red + (0 * 16 + r) * RSTR + w * 2) = make_float2(s[0], t[0]);
        *(float2*)(red + (1 * 16 + r) * RSTR + w * 2) = make_float2(s[1], t[1]);
      }
      __syncthreads();   // also orders slab reads (GEMM) before slab writes below
      float mean[2], rstd[2];
#pragma unroll
      for (int nt = 0; nt < 2; ++nt) {
        int row = nt * 16 + r;
        float ts = 0.f, tq = 0.f;
#pragma unroll
        for (int p = 0; p < 4; ++p) {
          f32x4 a = *(const f32x4*)(red + row * RSTR + p * 4);
          ts += a.x + a.z; tq += a.y + a.w;
        }
        mean[nt] = ts * (1.f / 512.f);
        rstd[nt] = rsqrtf(tq * (1.f / 512.f) - mean[nt] * mean[nt] + 1e-6f);
      }
      float gs[4][4], gb[4][4];
#pragma unroll
      for (int ci = 0; ci < 4; ++ci) {
        int cb = w * 64 + ci * 16 + q * 4;
#pragma unroll
        for (int j = 0; j < 4; ++j) {
          gs[ci][j] = ldp(psl, cb + j, f32);
          gb[ci][j] = ldp(plb, cb + j, f32);
        }
      }
#pragma unroll
      for (int ci = 0; ci < 4; ++ci) {
        int cb = w * 64 + ci * 16 + q * 4;
#pragma unroll
        for (int nt = 0; nt < 2; ++nt) {
          int row = nt * 16 + r;
          f32x4 v = acc[ci][nt];
          ushort4 o;
          o.x = __half_as_ushort(__float2half((v.x - mean[nt]) * rstd[nt] * gs[ci][0] + gb[ci][0]));
          o.y = __half_as_ushort(__float2half((v.y - mean[nt]) * rstd[nt] * gs[ci][1] + gb[ci][1]));
          o.z = __half_as_ushort(__float2half((v.z - mean[nt]) * rstd[nt] * gs[ci][2] + gb[ci][2]));
          o.w = __half_as_ushort(__float2half((v.w - mean[nt]) * rstd[nt] * gs[ci][3] + gb[ci][3]));
          *(ushort4*)(slab + row * SSTR + cb) = o;
        }
      }
      __syncthreads();
    } else {
      // ---- layer 3: bias only; store phi as fp16 ----
#pragma unroll
      for (int ci = 0; ci < 4; ++ci) {
        int cb = w * 64 + ci * 16 + q * 4;
        float bx = ldp(b3, cb + 0, f32), by = ldp(b3, cb + 1, f32);
        float bz2 = ldp(b3, cb + 2, f32), bw = ldp(b3, cb + 3, f32);
#pragma unroll
        for (int nt = 0; nt < 2; ++nt) {
          int row = nt * 16 + r;
          f32x4 v = acc[ci][nt];
          ushort4 o;
          o.x = __half_as_ushort(__float2half(v.x + bx));
          o.y = __half_as_ushort(__float2half(v.y + by));
          o.z = __half_as_ushort(__float2half(v.z + bz2));
          o.w = __half_as_ushort(__float2half(v.w + bw));
          *(ushort4*)(slab + row * SSTR + cb) = o;
        }
      }
      __syncthreads();
    }
  }

  // ---------------- IQE head ----------------
  {
    const float al = ldp(alphap, 0, f32);
    const float a = 1.f / (1.f + __expf(-al));
    const int h = lane >> 5, il = lane & 31;    // two components per wave
    for (int v = 0; v < 2; ++v) {
      int pL = 2 * w + v;                       // block-local pair 0..15
      float cs = 0.f, cm = 0.f;
      for (int it = 0; it < 8; ++it) {
        int c = 2 * it + h;                     // component 0..15
        float x = __half2float(__ushort_as_half(slab[(2 * pL) * SSTR + c * 32 + il]));
        float y = __half2float(__ushort_as_half(slab[(2 * pL + 1) * SSTR + c * 32 + il]));
        if (!(x < y)) y = NEG_INF;              // invalid interval -> empty
        // bitonic sort (x asc) across each 32-lane half, y rides along
#pragma unroll
        for (int k = 2; k <= 32; k <<= 1) {
#pragma unroll
          for (int j = k >> 1; j >= 1; j >>= 1) {
            float xo = __shfl_xor(x, j, 64);
            float yo = __shfl_xor(y, j, 64);
            bool keep_min = (((il & k) == 0) == ((il & j) == 0));
            bool take = keep_min ? (xo < x) : (xo > x);
            if (take) { x = xo; y = yo; }
          }
        }
        // exclusive prefix-max of y in start-sorted order
        float p = __shfl_up(y, 1, 32);
        if (il == 0) p = NEG_INF;
#pragma unroll
        for (int d = 1; d <= 16; d <<= 1) {
          float t2 = __shfl_up(p, d, 32);
          if (il >= d) p = fmaxf(p, t2);
        }
        float contrib = fmaxf(0.f, y - fmaxf(x, p));
#pragma unroll
        for (int msk = 1; msk <= 16; msk <<= 1)
          contrib += __shfl_xor(contrib, msk, 64);
        cs += contrib;
        cm = fmaxf(cm, contrib);
      }
      cs += __shfl_xor(cs, 32, 64);
      cm = fmaxf(cm, __shfl_xor(cm, 32, 64));
      if (lane == 0) {
        float res = a * (cs * (1.f / 16.f)) + (1.f - a) * cm;
        if (f32) ((float*)out)[i0 + pL] = res;
        else ((u16*)out)[i0 + pL] = f2bf(res);
      }
    }
  }
}

extern "C" void kernel_launch(void* const* d_in, const int* in_sizes, int n_in,
                              void* d_out, int out_size, void* d_ws, size_t ws_size,
                              hipStream_t stream) {
  (void)in_sizes; (void)n_in; (void)out_size; (void)ws_size;
  const void* obs   = d_in[0];
  const void* goals = d_in[1];
  const void* W0 = d_in[2];
  const void* b0 = d_in[3];
  const void* ls0 = d_in[4];
  const void* lb0 = d_in[5];
  const void* W1 = d_in[6];
  const void* b1 = d_in[7];
  const void* ls1 = d_in[8];
  const void* lb1 = d_in[9];
  const void* W2 = d_in[10];
  const void* b2 = d_in[11];
  const void* ls2 = d_in[12];
  const void* lb2 = d_in[13];
  const void* W3 = d_in[14];
  const void* b3 = d_in[15];
  const void* alpha = d_in[16];

  int* flag = (int*)d_ws;
  u16* wT0 = (u16*)((char*)d_ws + 64);
  u16* wT1 = wT0 + 512 * 64;
  u16* wT2 = wT1 + 512 * 512;
  u16* wT3 = wT2 + 512 * 512;

  detect_dtype<<<1, 64, 0, stream>>>((const u16*)obs, flag);
  pack_w<<<128, 256, 0, stream>>>(W0, wT0, flag, 512 * 64, 6, 63);
  pack_w<<<1024, 256, 0, stream>>>(W1, wT1, flag, 512 * 512, 9, 511);
  pack_w<<<1024, 256, 0, stream>>>(W2, wT2, flag, 512 * 512, 9, 511);
  pack_w<<<1024, 256, 0, stream>>>(W3, wT3, flag, 512 * 512, 9, 511);
  gciqe_main<<<8192, 512, 0, stream>>>(obs, goals, wT0, wT1, wT2, wT3,
      b0, b1, b2, b3, ls0, lb0, ls1, lb1, ls2, lb2, alpha, d_out, flag);
}

// Round 5
// 1143.308 us; speedup vs baseline: 1.7462x; 1.7460x over previous
//
#include <hip/hip_runtime.h>
#include <hip/hip_bf16.h>
#include <hip/hip_fp16.h>

typedef unsigned short u16;
typedef unsigned int u32;
typedef __attribute__((ext_vector_type(8))) _Float16 f16x8;
typedef __attribute__((ext_vector_type(4))) float f32x4;

#define ROWS 32          // 16 s/g pairs per block
#define SSTR 520         // slab stride in u16
#define RSTR 20          // red stride in floats (16B-aligned, bank-spread)
#define NEG_INF (-3.0e38f)

__device__ __forceinline__ float bf2f(u16 b) {
  union { u32 u; float f; } c; c.u = ((u32)b) << 16; return c.f;
}
__device__ __forceinline__ u16 f2bf(float f) {
  union { float f; u32 u; } c; c.f = f;
  u32 r = c.u + 0x7FFFu + ((c.u >> 16) & 1u);
  return (u16)(r >> 16);
}
__device__ __forceinline__ float gelu_tanh(float x) {
  // jax.nn.gelu approximate=True
  float u = 0.7978845608028654f * (x + 0.044715f * x * x * x);
  float e = __expf(2.f * u);
  float t = 1.f - 2.f / (e + 1.f);
  return 0.5f * x * (1.f + t);
}
// load a scalar param that may be fp32 or bf16
__device__ __forceinline__ float ldp(const void* p, int i, int f32) {
  return f32 ? ((const float*)p)[i] : bf2f(((const u16*)p)[i]);
}
// load 8 consecutive elements (fp32 or bf16) as f16x8 (vectorized)
__device__ __forceinline__ f16x8 load8(const void* base, long off, int f32) {
  f16x8 r;
  if (f32) {
    const float4* p = (const float4*)((const float*)base + off);
    float4 a = p[0], b = p[1];
    r[0] = (_Float16)a.x; r[1] = (_Float16)a.y; r[2] = (_Float16)a.z; r[3] = (_Float16)a.w;
    r[4] = (_Float16)b.x; r[5] = (_Float16)b.y; r[6] = (_Float16)b.z; r[7] = (_Float16)b.w;
  } else {
    const u16* p = (const u16*)base + off;
#pragma unroll
    for (int i = 0; i < 8; ++i) r[i] = (_Float16)bf2f(p[i]);
  }
  return r;
}

// one wave: decide whether inputs are fp32 (flag=1) or bf16 (flag=0).
__global__ void detect_dtype(const u16* __restrict__ obs, int* flag) {
  int l = threadIdx.x;
  float v = fabsf(bf2f(obs[2 * l]));
  if (v != v) v = 1e30f;  // NaN pattern also implies fp32
#pragma unroll
  for (int m = 1; m <= 32; m <<= 1) v = fmaxf(v, __shfl_xor(v, m, 64));
  if (l == 0) *flag = (v > 1000.0f) ? 1 : 0;
}

// Pack W [K x 512] into MFMA-fragment-major order (fp16):
// dst[((w*4+ci)*nk + t)*512 + lane*8 + j] = W[k][ch],
//   ch = w*64 + ci*16 + (lane&15), k = t*32 + (lane>>4)*8 + j.
// A hot-loop fragment load is then base + frag*1024B + lane*16B: fully coalesced.
__global__ void pack_frag(const void* __restrict__ src, u16* __restrict__ dst,
                          const int* __restrict__ flag, int total,
                          int fshift, int cishift, int tmask) {
  int id = blockIdx.x * 256 + threadIdx.x;
  if (id >= total) return;
  int j = id & 7;
  int lane = (id >> 3) & 63;
  int fi = id >> 9;
  int w = fi >> fshift;
  int rem = fi & ((1 << fshift) - 1);
  int ci = rem >> cishift;
  int t = rem & tmask;
  int q = lane >> 4, r = lane & 15;
  int ch = w * 64 + ci * 16 + r;
  int k = t * 32 + q * 8 + j;
  float v = ldp(src, k * 512 + ch, *flag);
  dst[id] = __half_as_ushort(__float2half(v));
}

__global__ __launch_bounds__(512, 4) void gciqe_main(
    const void* __restrict__ obs, const void* __restrict__ goals,
    const u16* __restrict__ wT0, const u16* __restrict__ wT1,
    const u16* __restrict__ wT2, const u16* __restrict__ wT3,
    const void* __restrict__ b0, const void* __restrict__ b1,
    const void* __restrict__ b2, const void* __restrict__ b3,
    const void* __restrict__ ls0, const void* __restrict__ lb0,
    const void* __restrict__ ls1, const void* __restrict__ lb1,
    const void* __restrict__ ls2, const void* __restrict__ lb2,
    const void* __restrict__ alphap, void* __restrict__ out,
    const int* __restrict__ flagp)
{
  __shared__ __align__(16) u16 slab[ROWS * SSTR];   // activations / phi, fp16 bits
  __shared__ __align__(16) float red[ROWS * RSTR];  // LN partials [row][wave]{s,t}

  const int f32 = *flagp;
  const int tid = threadIdx.x;
  const int lane = tid & 63, w = tid >> 6;      // 8 waves = 8 groups of 64 ch
  const int r = lane & 15, q = lane >> 4;
  const int i0 = blockIdx.x * 16;               // 16 pairs per block

  f32x4 acc[4][2];                              // [ci: 16-ch group][nt: row half]

  // ---------------- layer 0: [32 x 64] @ W0 -> acc ----------------
#pragma unroll
  for (int ci = 0; ci < 4; ++ci) {
    acc[ci][0] = (f32x4){0.f, 0.f, 0.f, 0.f};
    acc[ci][1] = (f32x4){0.f, 0.f, 0.f, 0.f};
  }
  {
    f16x8 bf0[2][2];
#pragma unroll
    for (int nt = 0; nt < 2; ++nt) {
      int row = nt * 16 + r;                    // even = obs, odd = goals
      const void* base = (row & 1) ? goals : obs;
      long ro = (long)(i0 + (row >> 1)) * 64;
#pragma unroll
      for (int u = 0; u < 2; ++u)
        bf0[nt][u] = load8(base, ro + u * 32 + q * 8, f32);
    }
    const u16* w0base = wT0 + w * 4096;         // 8 frags of 512 u16 per wave
#pragma unroll
    for (int ci = 0; ci < 4; ++ci) {
#pragma unroll
      for (int u = 0; u < 2; ++u) {
        f16x8 af = *(const f16x8*)(w0base + (ci * 2 + u) * 512 + lane * 8);
        acc[ci][0] = __builtin_amdgcn_mfma_f32_16x16x32_f16(af, bf0[0][u], acc[ci][0], 0, 0, 0);
        acc[ci][1] = __builtin_amdgcn_mfma_f32_16x16x32_f16(af, bf0[1][u], acc[ci][1], 0, 0, 0);
      }
    }
  }

  // ---------------- layers 0..2 epilogue + layers 1..3 GEMM ----------------
  for (int l = 0; l <= 3; ++l) {
    if (l > 0) {
      const u16* wp = (l == 1) ? wT1 : (l == 2) ? wT2 : wT3;
      const u16* wbase = wp + w * 32768;        // 64 frags of 512 u16 per wave
#pragma unroll
      for (int ci = 0; ci < 4; ++ci) {
        acc[ci][0] = (f32x4){0.f, 0.f, 0.f, 0.f};
        acc[ci][1] = (f32x4){0.f, 0.f, 0.f, 0.f};
      }
      // register double-buffer over (kq,ci) steps; frag f = ci*16 + kq*4 + u
      f16x8 A[2][4];
#pragma unroll
      for (int u = 0; u < 4; ++u)
        A[0][u] = *(const f16x8*)(wbase + u * 512 + lane * 8);   // ci=0,kq=0
#pragma unroll
      for (int kq = 0; kq < 4; ++kq) {          // K in chunks of 128
        f16x8 bfr[2][4];
#pragma unroll
        for (int nt = 0; nt < 2; ++nt)
#pragma unroll
          for (int u = 0; u < 4; ++u)
            bfr[nt][u] = *(const f16x8*)(slab + (nt * 16 + r) * SSTR + kq * 128 + u * 32 + q * 8);
#pragma unroll
        for (int ci = 0; ci < 4; ++ci) {
          const int step = kq * 4 + ci;
          const int cur = step & 1;
          if (step < 15) {
            const int nstep = step + 1;
            const int nci = nstep & 3, nkq = nstep >> 2;
#pragma unroll
            for (int u = 0; u < 4; ++u)
              A[cur ^ 1][u] = *(const f16x8*)(wbase + (nci * 16 + nkq * 4 + u) * 512 + lane * 8);
          }
#pragma unroll
          for (int u = 0; u < 4; ++u) {
            acc[ci][0] = __builtin_amdgcn_mfma_f32_16x16x32_f16(A[cur][u], bfr[0][u], acc[ci][0], 0, 0, 0);
            acc[ci][1] = __builtin_amdgcn_mfma_f32_16x16x32_f16(A[cur][u], bfr[1][u], acc[ci][1], 0, 0, 0);
          }
        }
      }
    }

    if (l < 3) {
      // ---- bias + gelu + LayerNorm -> slab (fp16) ----
      const void* pb  = (l == 0) ? b0 : (l == 1) ? b1 : b2;
      const void* psl = (l == 0) ? ls0 : (l == 1) ? ls1 : ls2;
      const void* plb = (l == 0) ? lb0 : (l == 1) ? lb1 : lb2;
      float bz[4][4];
#pragma unroll
      for (int ci = 0; ci < 4; ++ci) {
        int cb = w * 64 + ci * 16 + q * 4;
#pragma unroll
        for (int j = 0; j < 4; ++j) bz[ci][j] = ldp(pb, cb + j, f32);
      }
      float s[2] = {0.f, 0.f}, t[2] = {0.f, 0.f};
#pragma unroll
      for (int ci = 0; ci < 4; ++ci)
#pragma unroll
        for (int nt = 0; nt < 2; ++nt) {
          f32x4 v = acc[ci][nt];
          v.x = gelu_tanh(v.x + bz[ci][0]); v.y = gelu_tanh(v.y + bz[ci][1]);
          v.z = gelu_tanh(v.z + bz[ci][2]); v.w = gelu_tanh(v.w + bz[ci][3]);
          acc[ci][nt] = v;
          s[nt] += v.x + v.y + v.z + v.w;
          t[nt] += v.x * v.x + v.y * v.y + v.z * v.z + v.w * v.w;
        }
#pragma unroll
      for (int nt = 0; nt < 2; ++nt) {
        s[nt] += __shfl_xor(s[nt], 16, 64); t[nt] += __shfl_xor(t[nt], 16, 64);
        s[nt] += __shfl_xor(s[nt], 32, 64); t[nt] += __shfl_xor(t[nt], 32, 64);
      }
      if (q == 0) {
        *(float2*)(red + (0 * 16 + r) * RSTR + w * 2) = make_float2(s[0], t[0]);
        *(float2*)(red + (1 * 16 + r) * RSTR + w * 2) = make_float2(s[1], t[1]);
      }
      __syncthreads();   // also orders slab reads (GEMM) before slab writes below
      float mean[2], rstd[2];
#pragma unroll
      for (int nt = 0; nt < 2; ++nt) {
        int row = nt * 16 + r;
        float ts = 0.f, tq = 0.f;
#pragma unroll
        for (int p = 0; p < 4; ++p) {
          f32x4 a = *(const f32x4*)(red + row * RSTR + p * 4);
          ts += a.x + a.z; tq += a.y + a.w;
        }
        mean[nt] = ts * (1.f / 512.f);
        rstd[nt] = rsqrtf(tq * (1.f / 512.f) - mean[nt] * mean[nt] + 1e-6f);
      }
      float gs[4][4], gb[4][4];
#pragma unroll
      for (int ci = 0; ci < 4; ++ci) {
        int cb = w * 64 + ci * 16 + q * 4;
#pragma unroll
        for (int j = 0; j < 4; ++j) {
          gs[ci][j] = ldp(psl, cb + j, f32);
          gb[ci][j] = ldp(plb, cb + j, f32);
        }
      }
#pragma unroll
      for (int ci = 0; ci < 4; ++ci) {
        int cb = w * 64 + ci * 16 + q * 4;
#pragma unroll
        for (int nt = 0; nt < 2; ++nt) {
          int row = nt * 16 + r;
          f32x4 v = acc[ci][nt];
          ushort4 o;
          o.x = __half_as_ushort(__float2half((v.x - mean[nt]) * rstd[nt] * gs[ci][0] + gb[ci][0]));
          o.y = __half_as_ushort(__float2half((v.y - mean[nt]) * rstd[nt] * gs[ci][1] + gb[ci][1]));
          o.z = __half_as_ushort(__float2half((v.z - mean[nt]) * rstd[nt] * gs[ci][2] + gb[ci][2]));
          o.w = __half_as_ushort(__float2half((v.w - mean[nt]) * rstd[nt] * gs[ci][3] + gb[ci][3]));
          *(ushort4*)(slab + row * SSTR + cb) = o;
        }
      }
      __syncthreads();
    } else {
      // ---- layer 3: bias only; store phi as fp16 ----
#pragma unroll
      for (int ci = 0; ci < 4; ++ci) {
        int cb = w * 64 + ci * 16 + q * 4;
        float bx = ldp(b3, cb + 0, f32), by = ldp(b3, cb + 1, f32);
        float bz2 = ldp(b3, cb + 2, f32), bw = ldp(b3, cb + 3, f32);
#pragma unroll
        for (int nt = 0; nt < 2; ++nt) {
          int row = nt * 16 + r;
          f32x4 v = acc[ci][nt];
          ushort4 o;
          o.x = __half_as_ushort(__float2half(v.x + bx));
          o.y = __half_as_ushort(__float2half(v.y + by));
          o.z = __half_as_ushort(__float2half(v.z + bz2));
          o.w = __half_as_ushort(__float2half(v.w + bw));
          *(ushort4*)(slab + row * SSTR + cb) = o;
        }
      }
      __syncthreads();
    }
  }

  // ---------------- IQE head ----------------
  {
    const float al = ldp(alphap, 0, f32);
    const float a = 1.f / (1.f + __expf(-al));
    const int h = lane >> 5, il = lane & 31;    // two components per wave
    for (int v = 0; v < 2; ++v) {
      int pL = 2 * w + v;                       // block-local pair 0..15
      float cs = 0.f, cm = 0.f;
      for (int it = 0; it < 8; ++it) {
        int c = 2 * it + h;                     // component 0..15
        float x = __half2float(__ushort_as_half(slab[(2 * pL) * SSTR + c * 32 + il]));
        float y = __half2float(__ushort_as_half(slab[(2 * pL + 1) * SSTR + c * 32 + il]));
        if (!(x < y)) y = NEG_INF;              // invalid interval -> empty
        // bitonic sort (x asc) across each 32-lane half, y rides along
#pragma unroll
        for (int k = 2; k <= 32; k <<= 1) {
#pragma unroll
          for (int j = k >> 1; j >= 1; j >>= 1) {
            float xo = __shfl_xor(x, j, 64);
            float yo = __shfl_xor(y, j, 64);
            bool keep_min = (((il & k) == 0) == ((il & j) == 0));
            bool take = keep_min ? (xo < x) : (xo > x);
            if (take) { x = xo; y = yo; }
          }
        }
        // exclusive prefix-max of y in start-sorted order
        float p = __shfl_up(y, 1, 32);
        if (il == 0) p = NEG_INF;
#pragma unroll
        for (int d = 1; d <= 16; d <<= 1) {
          float t2 = __shfl_up(p, d, 32);
          if (il >= d) p = fmaxf(p, t2);
        }
        float contrib = fmaxf(0.f, y - fmaxf(x, p));
#pragma unroll
        for (int msk = 1; msk <= 16; msk <<= 1)
          contrib += __shfl_xor(contrib, msk, 64);
        cs += contrib;
        cm = fmaxf(cm, contrib);
      }
      cs += __shfl_xor(cs, 32, 64);
      cm = fmaxf(cm, __shfl_xor(cm, 32, 64));
      if (lane == 0) {
        float res = a * (cs * (1.f / 16.f)) + (1.f - a) * cm;
        if (f32) ((float*)out)[i0 + pL] = res;
        else ((u16*)out)[i0 + pL] = f2bf(res);
      }
    }
  }
}

extern "C" void kernel_launch(void* const* d_in, const int* in_sizes, int n_in,
                              void* d_out, int out_size, void* d_ws, size_t ws_size,
                              hipStream_t stream) {
  (void)in_sizes; (void)n_in; (void)out_size; (void)ws_size;
  const void* obs   = d_in[0];
  const void* goals = d_in[1];
  const void* W0 = d_in[2];
  const void* b0 = d_in[3];
  const void* ls0 = d_in[4];
  const void* lb0 = d_in[5];
  const void* W1 = d_in[6];
  const void* b1 = d_in[7];
  const void* ls1 = d_in[8];
  const void* lb1 = d_in[9];
  const void* W2 = d_in[10];
  const void* b2 = d_in[11];
  const void* ls2 = d_in[12];
  const void* lb2 = d_in[13];
  const void* W3 = d_in[14];
  const void* b3 = d_in[15];
  const void* alpha = d_in[16];

  int* flag = (int*)d_ws;
  u16* wT0 = (u16*)((char*)d_ws + 64);
  u16* wT1 = wT0 + 512 * 64;
  u16* wT2 = wT1 + 512 * 512;
  u16* wT3 = wT2 + 512 * 512;

  detect_dtype<<<1, 64, 0, stream>>>((const u16*)obs, flag);
  // layer0: K=64, nk=2: fshift=3 (4*nk=8 frags/wave), cishift=1, tmask=1
  pack_frag<<<128, 256, 0, stream>>>(W0, wT0, flag, 512 * 64, 3, 1, 1);
  // layers1-3: K=512, nk=16: fshift=6 (64 frags/wave), cishift=4, tmask=15
  pack_frag<<<1024, 256, 0, stream>>>(W1, wT1, flag, 512 * 512, 6, 4, 15);
  pack_frag<<<1024, 256, 0, stream>>>(W2, wT2, flag, 512 * 512, 6, 4, 15);
  pack_frag<<<1024, 256, 0, stream>>>(W3, wT3, flag, 512 * 512, 6, 4, 15);
  gciqe_main<<<8192, 512, 0, stream>>>(obs, goals, wT0, wT1, wT2, wT3,
      b0, b1, b2, b3, ls0, lb0, ls1, lb1, ls2, lb2, alpha, d_out, flag);
}